// Round 1
// 535.367 us; speedup vs baseline: 1.0435x; 1.0435x over previous
//
#include <hip/hip_runtime.h>
#include <hip/hip_bf16.h>
#include <stdint.h>

// MaskedDeepDAN on MI355X (gfx950). B=8192, D_IN=2048, H=1024, C=1000.
// R7: replace the 2-barrier-per-K-step 128x128 GEMM (MfmaUtil 23%, full
// vmcnt drain at every __syncthreads) with the phase-split counted-vmcnt
// schedule (T3+T4+T5):
//   - BM=256 x BN=128 x BK=64, 512 threads / 8 waves (4Mx2N), 64x64 per wave
//   - grid 256 = 1 block/CU; bijective XCD remap (4 M-panels x 8 N-tiles/XCD)
//   - LDS 96KB: 2 x (A 32KB + B 16KB) double buffer; 6 global_load_lds/tile
//     linear LDS dest + inverse-XOR-swizzled global src (slot ^ row&7);
//     fragment ds_read_b128 applies the same XOR -> uniform 8 lanes/slot
//   - 4 phases/K-tile: {ds_read; s_barrier; lgkmcnt(0); setprio(1); 8 MFMA;
//     setprio(0); s_barrier}; next-next tile staged under phase 3
//   - s_waitcnt vmcnt(6) per tile (never 0 in main loop); raw s_barrier asm
//     (no __syncthreads drain anywhere in the K-loop)
//   - per-source biases preloaded to regs (keeps vmcnt accounting exact)
// Carried verified R3-R6: per-layer fused multi-source GEMM + bias/relu
// epilogue, prep/detect pipeline, size-signature resolver, store layout.

typedef unsigned short ushort_t;
typedef __bf16 bf16x8 __attribute__((ext_vector_type(8)));
typedef float f32x4 __attribute__((ext_vector_type(4)));

__device__ __forceinline__ void gl_lds16(const void* g, void* l) {
  typedef __attribute__((address_space(1))) void gvoid;
  typedef __attribute__((address_space(3))) void lvoid;
  __builtin_amdgcn_global_load_lds((gvoid*)(void*)g, (lvoid*)l, 16, 0, 0);
}

__device__ __forceinline__ ushort_t f2b(float f) {
  __hip_bfloat16 h = (__hip_bfloat16)f;
  return *(ushort_t*)&h;
}

// ---------------- dtype detection (verified R3) ----------------
// flags[0] = 1 if floats are fp32, 0 if bf16
// flags[1] = mask mode: 0=int32, 1=uint8, 2=bf16(u16), 3=fp32
__global__ void detect_kernel(const ushort_t* x, const ushort_t* mf, int* flags) {
  __shared__ int s[4];
  if (threadIdx.x < 4) s[threadIdx.x] = 0;
  __syncthreads();
  int expout = 0, m3f80_even = 0, m3f80_odd = 0, mhi01 = 0;
  for (int k = threadIdx.x; k < 2048; k += 256) {
    ushort_t w = x[k];
    int e = (w >> 7) & 0xFF;
    if (e < 96 || e > 144) expout++;
    ushort_t mw = mf[k];
    if (mw == 0x3F80) { if (k & 1) m3f80_odd++; else m3f80_even++; }
    if ((mw >> 8) == 1) mhi01++;
  }
  atomicAdd(&s[0], expout);
  atomicAdd(&s[1], m3f80_even);
  atomicAdd(&s[2], m3f80_odd);
  atomicAdd(&s[3], mhi01);
  __syncthreads();
  if (threadIdx.x == 0) {
    flags[0] = (s[0] > 100) ? 1 : 0;
    int mmode = 0;
    if (s[1] > 100) mmode = 2;
    else if (s[2] > 100) mmode = 3;
    else if (s[3] > 200) mmode = 1;
    flags[1] = mmode;
  }
}

// -------- masking + dtype conversion (weights, biases, and x) --------
struct PrepEnt {
  const void* w; size_t woff;
  const void* m; size_t moff;   // nullptr -> no mask
  ushort_t* o;
  int n;
  int valid;                    // i >= valid -> 0
};
struct PrepAll { PrepEnt e[25]; };

__global__ void prep_weights(PrepAll p, const int* flags) {
  const bool f32 = flags[0] != 0;
  const int mmode = flags[1];
  const PrepEnt e = p.e[blockIdx.y];
  const int nch = e.n >> 3;
  const int stride = blockDim.x * gridDim.x;
  for (int ci = blockIdx.x * blockDim.x + threadIdx.x; ci < nch; ci += stride) {
    const int i = ci << 3;
    ushort_t o[8] = {0, 0, 0, 0, 0, 0, 0, 0};
    if (i < e.valid) {
      ushort_t wb[8];
      if (f32) {
        const float* wp = (const float*)e.w + e.woff + i;
        float4 a = *(const float4*)wp;
        float4 b = *(const float4*)(wp + 4);
        wb[0] = f2b(a.x); wb[1] = f2b(a.y); wb[2] = f2b(a.z); wb[3] = f2b(a.w);
        wb[4] = f2b(b.x); wb[5] = f2b(b.y); wb[6] = f2b(b.z); wb[7] = f2b(b.w);
      } else {
        *(uint4*)wb = *(const uint4*)((const ushort_t*)e.w + e.woff + i);
      }
      unsigned mk = 0xFF;
      if (e.m) {
        mk = 0;
        if (mmode == 0) {
          const int4* mp = (const int4*)((const int*)e.m + e.moff + i);
          int4 a = mp[0], b = mp[1];
          mk = (a.x != 0) | ((a.y != 0) << 1) | ((a.z != 0) << 2) | ((a.w != 0) << 3) |
               ((b.x != 0) << 4) | ((b.y != 0) << 5) | ((b.z != 0) << 6) | ((b.w != 0) << 7);
        } else if (mmode == 1) {
          const uint2 mv = *(const uint2*)((const unsigned char*)e.m + e.moff + i);
          const unsigned char* mb = (const unsigned char*)&mv;
          for (int j = 0; j < 8; j++) mk |= (mb[j] != 0) << j;
        } else if (mmode == 2) {
          uint4 mv = *(const uint4*)((const ushort_t*)e.m + e.moff + i);
          const ushort_t* ms = (const ushort_t*)&mv;
          for (int j = 0; j < 8; j++) mk |= (ms[j] != 0) << j;
        } else {
          const uint4* mp = (const uint4*)((const unsigned int*)e.m + e.moff + i);
          uint4 a = mp[0], b = mp[1];
          const unsigned* u = (const unsigned*)&a;
          const unsigned* v = (const unsigned*)&b;
          for (int j = 0; j < 4; j++) mk |= (u[j] != 0) << j;
          for (int j = 0; j < 4; j++) mk |= (v[j] != 0) << (4 + j);
        }
      }
#pragma unroll
      for (int j = 0; j < 8; j++) o[j] = ((mk >> j) & 1) ? wb[j] : (ushort_t)0;
    }
    *(uint4*)(e.o + i) = *(uint4*)o;
  }
}

// ---------------- fused multi-source GEMM, phase-split pipeline ----------------
// C[M,N] = sum_s relu(A_s[M,K] * B_s[N,K]^T + bias_s)
// grid = 256 blocks (BM=256 x BN=128 over M=8192, N_pad=1024), block = 512.
struct GemmSrc { const ushort_t* A; const ushort_t* B; const ushort_t* bias; };
struct GemmArgs { GemmSrc s[4]; };

#define SBAR()  asm volatile("s_barrier" ::: "memory")
#define LGKM0() asm volatile("s_waitcnt lgkmcnt(0)" ::: "memory")
#define VMC6()  asm volatile("s_waitcnt vmcnt(6)" ::: "memory")
#define VMC0()  asm volatile("s_waitcnt vmcnt(0)" ::: "memory")

template <int NSRC, bool RELU, bool NGUARD>
__launch_bounds__(512, 2)
__global__ void gemm_multi(GemmArgs args, void* Cv, const int* of32flag,
                           int K, int N_real, int ldc)
{
  // per buffer: A 256x64 bf16 (16384 el) + B 128x64 bf16 (8192 el) = 48KB
  __shared__ __align__(16) ushort_t lds[2][24576];

  const bool of32 = (of32flag != nullptr) && (of32flag[0] != 0);
  __hip_bfloat16* C = (__hip_bfloat16*)Cv;
  float* Cf = (float*)Cv;

  const int tid  = threadIdx.x;
  const int lane = tid & 63;
  const int wave = tid >> 6;
  const int wm = (wave >> 1) * 64;   // 0,64,128,192
  const int wn = (wave & 1) * 64;    // 0,64
  const int fr = lane & 15;
  const int kg = lane >> 4;

  // XCD-aware remap (grid=256, nwg%8==0 -> bijective): XCD x = lid&7 owns
  // M-panels 4x..4x+3, each paired with all 8 N-tiles -> A panel hits its
  // XCD L2 once; B (2MB/source) L2-resident.
  const int lid = blockIdx.x;
  const int xcd = lid & 7, chunk = lid >> 3;
  const int bm = (xcd * 4 + (chunk >> 3)) * 256;
  const int bn = (chunk & 7) * 128;

  // -------- staging addressing: linear LDS dest, inverse-swizzled source.
  // thread t writes LDS row rbase, 16B-slot (t&7); global slot sg = (t&7)^(rbase&7).
  const int rbase = tid >> 3;               // 0..63 per call
  const int sg    = (tid & 7) ^ (rbase & 7);
  const size_t aoff = (size_t)(bm + rbase) * K + sg * 8;
  const size_t boff = (size_t)(bn + rbase) * K + sg * 8;
  const size_t rs64 = (size_t)64 * K;

  auto stage = [&](const ushort_t* gA, const ushort_t* gB, int buf) {
    ushort_t* base = &lds[buf][0];
    ushort_t* lA = base + wave * 512;            // A at elem 0
    ushort_t* lB = base + 16384 + wave * 512;    // B at elem 16384
    gl_lds16(gA,            lA);
    gl_lds16(gA + rs64,     lA + 4096);
    gl_lds16(gA + 2 * rs64, lA + 8192);
    gl_lds16(gA + 3 * rs64, lA + 12288);
    gl_lds16(gB,            lB);
    gl_lds16(gB + rs64,     lB + 4096);
  };

  // -------- fragment read addressing (XOR-swizzled, row&7 == fr&7) --------
  const int s0   = (kg ^ (fr & 7)) * 16;    // byte slot, ks=0; ks=1 -> ^64
  const int arow = (wm + fr) * 128;         // byte offset of A row
  const int brow = 32768 + (wn + fr) * 128; // byte offset of B row

  f32x4 acc[4][4], out_acc[4][4];
#pragma unroll
  for (int i = 0; i < 4; i++)
#pragma unroll
    for (int j = 0; j < 4; j++) {
      acc[i][j] = (f32x4){0.f, 0.f, 0.f, 0.f};
      if (NSRC > 1) out_acc[i][j] = (f32x4){0.f, 0.f, 0.f, 0.f};
    }

  // biases preloaded (keeps vmcnt accounting in the K-loop exact)
  float bpre[NSRC][4];
#pragma unroll
  for (int s = 0; s < NSRC; ++s)
#pragma unroll
    for (int ni = 0; ni < 4; ni++)
      bpre[s][ni] = (float)*(const __hip_bfloat16*)
          (args.s[s].bias + bn + wn + ni * 16 + fr);

  const int TPS = K >> 6;          // K-tiles per source (16 or 32)
  const int NT  = TPS * NSRC;

  // prologue: stage tiles 0,1; wait tile 0 (leave tile 1's 6 loads flying)
  stage(args.s[0].A + aoff, args.s[0].B + boff, 0);
  {
    const int s1 = 1 / TPS, k1 = (1 % TPS) * 64;
    stage(args.s[s1].A + aoff + k1, args.s[s1].B + boff + k1, 1);
  }
  VMC6();
  SBAR();

  int psrc = 2 / TPS, pk0 = (2 % TPS) * 64;  // next tile to stage
  int csrc = 0, ck = 0;
  int cur = 0;

  for (int t = 0; t < NT; ++t) {
    const char* Lb = (const char*)&lds[cur][0];
    bf16x8 aL[2][2], aH[2][2], bL[2][2], bH[2][2];

    // ---- phase 0: read A(mi0,1) + B(ni0,1); MFMA mi01 x ni01 ----
#pragma unroll
    for (int m = 0; m < 2; ++m)
#pragma unroll
      for (int ks = 0; ks < 2; ++ks)
        aL[m][ks] = *(const bf16x8*)(Lb + arow + m * 2048 + (s0 ^ (ks * 64)));
#pragma unroll
    for (int n = 0; n < 2; ++n)
#pragma unroll
      for (int ks = 0; ks < 2; ++ks)
        bL[n][ks] = *(const bf16x8*)(Lb + brow + n * 2048 + (s0 ^ (ks * 64)));
    SBAR();
    LGKM0();
    __builtin_amdgcn_s_setprio(1);
#pragma unroll
    for (int m = 0; m < 2; ++m)
#pragma unroll
      for (int n = 0; n < 2; ++n)
#pragma unroll
        for (int ks = 0; ks < 2; ++ks)
          acc[m][n] = __builtin_amdgcn_mfma_f32_16x16x32_bf16(
              aL[m][ks], bL[n][ks], acc[m][n], 0, 0, 0);
    __builtin_amdgcn_s_setprio(0);
    SBAR();

    // ---- phase 1: read B(ni2,3); MFMA mi01 x ni23 ----
#pragma unroll
    for (int n = 0; n < 2; ++n)
#pragma unroll
      for (int ks = 0; ks < 2; ++ks)
        bH[n][ks] = *(const bf16x8*)(Lb + brow + (n + 2) * 2048 + (s0 ^ (ks * 64)));
    SBAR();
    LGKM0();
    __builtin_amdgcn_s_setprio(1);
#pragma unroll
    for (int m = 0; m < 2; ++m)
#pragma unroll
      for (int n = 0; n < 2; ++n)
#pragma unroll
        for (int ks = 0; ks < 2; ++ks)
          acc[m][n + 2] = __builtin_amdgcn_mfma_f32_16x16x32_bf16(
              aL[m][ks], bH[n][ks], acc[m][n + 2], 0, 0, 0);
    __builtin_amdgcn_s_setprio(0);
    SBAR();

    // ---- phase 2: read A(mi2,3); MFMA mi23 x ni01 ----
#pragma unroll
    for (int m = 0; m < 2; ++m)
#pragma unroll
      for (int ks = 0; ks < 2; ++ks)
        aH[m][ks] = *(const bf16x8*)(Lb + arow + (m + 2) * 2048 + (s0 ^ (ks * 64)));
    SBAR();
    LGKM0();
    __builtin_amdgcn_s_setprio(1);
#pragma unroll
    for (int m = 0; m < 2; ++m)
#pragma unroll
      for (int n = 0; n < 2; ++n)
#pragma unroll
        for (int ks = 0; ks < 2; ++ks)
          acc[m + 2][n] = __builtin_amdgcn_mfma_f32_16x16x32_bf16(
              aH[m][ks], bL[n][ks], acc[m + 2][n], 0, 0, 0);
    __builtin_amdgcn_s_setprio(0);
    SBAR();

    // ---- phase 3 + transition: stage t+2 (buf cur is fully consumed —
    // all waves passed phase-2's barrier after dependency-retired reads),
    // MFMA mi23 x ni23, optional source epilogue, counted vmcnt ----
    ck += 64;
    const bool srcEnd = (ck == K);
    const bool more2 = (t + 2 < NT);
    if (more2) {
      stage(args.s[psrc].A + aoff + pk0, args.s[psrc].B + boff + pk0, cur);
      pk0 += 64; if (pk0 == K) { pk0 = 0; ++psrc; }
    }
    __builtin_amdgcn_s_setprio(1);
#pragma unroll
    for (int m = 0; m < 2; ++m)
#pragma unroll
      for (int n = 0; n < 2; ++n)
#pragma unroll
        for (int ks = 0; ks < 2; ++ks)
          acc[m + 2][n + 2] = __builtin_amdgcn_mfma_f32_16x16x32_bf16(
              aH[m][ks], bH[n][ks], acc[m + 2][n + 2], 0, 0, 0);
    __builtin_amdgcn_s_setprio(0);

    if (NSRC > 1 && srcEnd) {
      float bb[4];
#pragma unroll
      for (int s = 0; s < NSRC; ++s)
        if (s == csrc) {
#pragma unroll
          for (int ni = 0; ni < 4; ni++) bb[ni] = bpre[s][ni];
        }
#pragma unroll
      for (int ni = 0; ni < 4; ni++)
#pragma unroll
        for (int mi = 0; mi < 4; mi++)
#pragma unroll
          for (int j = 0; j < 4; j++) {
            float v = acc[mi][ni][j] + bb[ni];
            if (RELU) v = fmaxf(v, 0.0f);
            out_acc[mi][ni][j] += v;
            acc[mi][ni][j] = 0.0f;
          }
      ck = 0; ++csrc;
    }

    if (t + 1 < NT) {
      if (more2) VMC6(); else VMC0();
      SBAR();
    }
    cur ^= 1;
  }

  // store: C/D layout col = lane&15, row = (lane>>4)*4 + reg  (verified R3)
#pragma unroll
  for (int ni = 0; ni < 4; ni++) {
    const int c = bn + wn + ni * 16 + fr;
    if (NGUARD && c >= N_real) continue;
#pragma unroll
    for (int mi = 0; mi < 4; mi++) {
      const int r0 = bm + wm + mi * 16 + kg * 4;
#pragma unroll
      for (int j = 0; j < 4; j++) {
        const size_t idx = (size_t)(r0 + j) * ldc + c;
        float v;
        if (NSRC == 1) {
          v = acc[mi][ni][j] + bpre[0][ni];
          if (RELU) v = fmaxf(v, 0.0f);
        } else {
          v = out_acc[mi][ni][j];
        }
        if (of32) Cf[idx] = v;
        else      C[idx]  = (__hip_bfloat16)v;
      }
    }
  }
}

extern "C" void kernel_launch(void* const* d_in, const int* in_sizes, int n_in,
                              void* d_out, int out_size, void* d_ws, size_t ws_size,
                              hipStream_t stream) {
  (void)out_size; (void)ws_size;
  const int Bm = 8192, DIN = 2048, H = 1024, Cn = 1000;
  const size_t HH = (size_t)H * H;

  // ---- size-signature input resolver (verified R3) ----
  struct PO { const void* p; size_t off; };
  PO x{d_in[0], 0}, Wf{d_in[0], 0}, mf{d_in[0], 0}, Wo{d_in[0], 0}, mo{d_in[0], 0};
  PO bf{d_in[0], 0}, bo{d_in[0], 0};
  PO mW[4], mM[4], mB[4], sW[6], sM[6], sB[6];
  for (int i = 0; i < 4; i++) { mW[i] = {d_in[0], 0}; mM[i] = mW[i]; mB[i] = mW[i]; }
  for (int i = 0; i < 6; i++) { sW[i] = {d_in[0], 0}; sM[i] = sW[i]; sB[i] = sW[i]; }

  {
    int c2M = 0, c1M = 0, c1k = 0, cWoMo = 0, c4 = 0, c6 = 0;
    for (int i = 0; i < n_in; i++) {
      const int s = in_sizes[i];
      const void* p = d_in[i];
      switch (s) {
        case 16777216: x = {p, 0}; break;
        case 2097152:  if (c2M++ == 0) Wf = {p, 0}; else mf = {p, 0}; break;
        case 1048576: {
          int j = c1M++;
          if (j < 4)       mW[j]      = {p, 0};
          else if (j < 8)  mM[j - 4]  = {p, 0};
          else if (j < 14) sW[j - 8]  = {p, 0};
          else if (j < 20) sM[j - 14] = {p, 0};
          break;
        }
        case 1024: {
          int j = c1k++;
          if (j == 0)      bf        = {p, 0};
          else if (j < 5)  mB[j - 1] = {p, 0};
          else if (j < 11) sB[j - 5] = {p, 0};
          break;
        }
        case 1024000: if (cWoMo++ == 0) Wo = {p, 0}; else mo = {p, 0}; break;
        case 1000: bo = {p, 0}; break;
        case 4194304:
          for (int t = 0; t < 4; t++) {
            if (c4 == 0) mW[t] = {p, t * HH}; else mM[t] = {p, t * HH};
          }
          c4++; break;
        case 6291456:
          for (int t = 0; t < 6; t++) {
            if (c6 == 0) sW[t] = {p, t * HH}; else sM[t] = {p, t * HH};
          }
          c6++; break;
        case 4096:
          for (int t = 0; t < 4; t++) mB[t] = {p, (size_t)t * H};
          break;
        case 6144:
          for (int t = 0; t < 6; t++) sB[t] = {p, (size_t)t * H};
          break;
        default: break;
      }
    }
  }

  // ---- workspace layout (ushort units) ----
  ushort_t* wsp = (ushort_t*)d_ws;
  size_t off = 0;
  int* flags = (int*)wsp; off += 32;
  ushort_t* xc = wsp + off; off += (size_t)Bm * DIN;
  __hip_bfloat16* r[5];
  for (int i = 0; i < 5; i++) { r[i] = (__hip_bfloat16*)(wsp + off); off += (size_t)Bm * H; }
  ushort_t* wWf = wsp + off; off += (size_t)H * DIN;
  ushort_t* wMain[4];
  for (int i = 0; i < 4; i++) { wMain[i] = wsp + off; off += HH; }
  ushort_t* wSkip[6];
  for (int k = 0; k < 6; k++) { wSkip[k] = wsp + off; off += HH; }
  ushort_t* wWo = wsp + off; off += (size_t)1024 * 1024;  // zero-padded to 1024 rows
  ushort_t* cbf_ = wsp + off; off += 1024;
  ushort_t* cmB[4];
  for (int i = 0; i < 4; i++) { cmB[i] = wsp + off; off += 1024; }
  ushort_t* csB[6];
  for (int k = 0; k < 6; k++) { csB[k] = wsp + off; off += 1024; }
  ushort_t* cbo = wsp + off; off += 1024;                 // tail 1000..1023 zeroed

  // ---- launches ----
  detect_kernel<<<1, 256, 0, stream>>>((const ushort_t*)x.p, (const ushort_t*)mf.p, flags);

  PrepAll p;
  p.e[0]  = { Wf.p, Wf.off, mf.p, mf.off, wWf, H * DIN, H * DIN };
  for (int i = 0; i < 4; i++)
    p.e[1 + i] = { mW[i].p, mW[i].off, mM[i].p, mM[i].off, wMain[i], (int)HH, (int)HH };
  for (int k = 0; k < 6; k++)
    p.e[5 + k] = { sW[k].p, sW[k].off, sM[k].p, sM[k].off, wSkip[k], (int)HH, (int)HH };
  p.e[11] = { Wo.p, Wo.off, mo.p, mo.off, wWo, 1024 * 1024, Cn * H };
  p.e[12] = { bf.p, bf.off, nullptr, 0, cbf_, H, H };
  for (int i = 0; i < 4; i++)
    p.e[13 + i] = { mB[i].p, mB[i].off, nullptr, 0, cmB[i], H, H };
  for (int k = 0; k < 6; k++)
    p.e[17 + k] = { sB[k].p, sB[k].off, nullptr, 0, csB[k], H, H };
  p.e[23] = { bo.p, bo.off, nullptr, 0, cbo, 1024, Cn };
  p.e[24] = { x.p, x.off, nullptr, 0, xc, Bm * DIN, Bm * DIN };   // x conversion
  prep_weights<<<dim3(256, 25), dim3(256), 0, stream>>>(p, flags);

  const dim3 g(256), b(512);

  GemmArgs a0; a0.s[0] = { xc, wWf, cbf_ };
  gemm_multi<1, true, false><<<g, b, 0, stream>>>(a0, r[0], nullptr, DIN, H, H);

  GemmArgs a1; a1.s[0] = { (ushort_t*)r[0], wMain[0], cmB[0] };
  gemm_multi<1, true, false><<<g, b, 0, stream>>>(a1, r[1], nullptr, H, H, H);

  GemmArgs a2;
  a2.s[0] = { (ushort_t*)r[1], wMain[1], cmB[1] };
  a2.s[1] = { (ushort_t*)r[0], wSkip[0], csB[0] };
  gemm_multi<2, true, false><<<g, b, 0, stream>>>(a2, r[2], nullptr, H, H, H);

  GemmArgs a3;
  a3.s[0] = { (ushort_t*)r[2], wMain[2], cmB[2] };
  a3.s[1] = { (ushort_t*)r[0], wSkip[1], csB[1] };
  a3.s[2] = { (ushort_t*)r[1], wSkip[2], csB[2] };
  gemm_multi<3, true, false><<<g, b, 0, stream>>>(a3, r[3], nullptr, H, H, H);

  GemmArgs a4;
  a4.s[0] = { (ushort_t*)r[3], wMain[3], cmB[3] };
  a4.s[1] = { (ushort_t*)r[0], wSkip[3], csB[3] };
  a4.s[2] = { (ushort_t*)r[1], wSkip[4], csB[4] };
  a4.s[3] = { (ushort_t*)r[2], wSkip[5], csB[5] };
  gemm_multi<4, true, false><<<g, b, 0, stream>>>(a4, r[4], nullptr, H, H, H);

  GemmArgs ao; ao.s[0] = { (ushort_t*)r[4], wWo, cbo };
  gemm_multi<1, false, true><<<g, b, 0, stream>>>(ao, d_out, flags, H, Cn, Cn);
}

// Round 2
// 535.357 us; speedup vs baseline: 1.0435x; 1.0000x over previous
//
#include <hip/hip_runtime.h>
#include <hip/hip_bf16.h>
#include <stdint.h>

// MaskedDeepDAN on MI355X (gfx950). B=8192, D_IN=2048, H=1024, C=1000.
// R8: R7 post-mortem showed the 4-phase/9-barrier schedule SERIALIZED
// ds_read vs MFMA chip-wide (per-tile: 1032 cyc MFMA + ~1000-1500 cyc LDS
// reads + 9 barrier skews = 4128 measured; MfmaUtil 26%). Fix: one
// straight-line region per K-tile (16 ds_read_b128 + 32 MFMA, compiler
// emits fine-grained lgkmcnt interleave -> reads hide under MFMA), and only
// TWO barriers per tile:
//   [reads+MFMA] -> lgkmcnt(0) -> s_barrier (read-retirement fence, buffer
//   cur now reusable) -> stage(t+2 -> cur) -> vmcnt(6) (t+1's loads, issued
//   a full tile ago) -> s_barrier -> flip.
// Counted vmcnt never drains to 0 in the main loop (kept from R7).
// Geometry kept from R7 (single variable change): BM=256 x BN=128 x BK=64,
// 512 thr / 8 waves (4Mx2N, 64x64/wave), grid 256 = 1 block/CU, bijective
// XCD remap, 96KB LDS double buffer, XOR-swizzled staging (conflict-free,
// SQ_LDS_BANK_CONFLICT=0 verified R7), per-source bias preload, fused
// bias+relu multi-source epilogue. Prep/detect/resolver verified R3-R7.

typedef unsigned short ushort_t;
typedef __bf16 bf16x8 __attribute__((ext_vector_type(8)));
typedef float f32x4 __attribute__((ext_vector_type(4)));

__device__ __forceinline__ void gl_lds16(const void* g, void* l) {
  typedef __attribute__((address_space(1))) void gvoid;
  typedef __attribute__((address_space(3))) void lvoid;
  __builtin_amdgcn_global_load_lds((gvoid*)(void*)g, (lvoid*)l, 16, 0, 0);
}

__device__ __forceinline__ ushort_t f2b(float f) {
  __hip_bfloat16 h = (__hip_bfloat16)f;
  return *(ushort_t*)&h;
}

// ---------------- dtype detection (verified R3) ----------------
// flags[0] = 1 if floats are fp32, 0 if bf16
// flags[1] = mask mode: 0=int32, 1=uint8, 2=bf16(u16), 3=fp32
__global__ void detect_kernel(const ushort_t* x, const ushort_t* mf, int* flags) {
  __shared__ int s[4];
  if (threadIdx.x < 4) s[threadIdx.x] = 0;
  __syncthreads();
  int expout = 0, m3f80_even = 0, m3f80_odd = 0, mhi01 = 0;
  for (int k = threadIdx.x; k < 2048; k += 256) {
    ushort_t w = x[k];
    int e = (w >> 7) & 0xFF;
    if (e < 96 || e > 144) expout++;
    ushort_t mw = mf[k];
    if (mw == 0x3F80) { if (k & 1) m3f80_odd++; else m3f80_even++; }
    if ((mw >> 8) == 1) mhi01++;
  }
  atomicAdd(&s[0], expout);
  atomicAdd(&s[1], m3f80_even);
  atomicAdd(&s[2], m3f80_odd);
  atomicAdd(&s[3], mhi01);
  __syncthreads();
  if (threadIdx.x == 0) {
    flags[0] = (s[0] > 100) ? 1 : 0;
    int mmode = 0;
    if (s[1] > 100) mmode = 2;
    else if (s[2] > 100) mmode = 3;
    else if (s[3] > 200) mmode = 1;
    flags[1] = mmode;
  }
}

// -------- masking + dtype conversion (weights, biases, and x) --------
struct PrepEnt {
  const void* w; size_t woff;
  const void* m; size_t moff;   // nullptr -> no mask
  ushort_t* o;
  int n;
  int valid;                    // i >= valid -> 0
};
struct PrepAll { PrepEnt e[25]; };

__global__ void prep_weights(PrepAll p, const int* flags) {
  const bool f32 = flags[0] != 0;
  const int mmode = flags[1];
  const PrepEnt e = p.e[blockIdx.y];
  const int nch = e.n >> 3;
  const int stride = blockDim.x * gridDim.x;
  for (int ci = blockIdx.x * blockDim.x + threadIdx.x; ci < nch; ci += stride) {
    const int i = ci << 3;
    ushort_t o[8] = {0, 0, 0, 0, 0, 0, 0, 0};
    if (i < e.valid) {
      ushort_t wb[8];
      if (f32) {
        const float* wp = (const float*)e.w + e.woff + i;
        float4 a = *(const float4*)wp;
        float4 b = *(const float4*)(wp + 4);
        wb[0] = f2b(a.x); wb[1] = f2b(a.y); wb[2] = f2b(a.z); wb[3] = f2b(a.w);
        wb[4] = f2b(b.x); wb[5] = f2b(b.y); wb[6] = f2b(b.z); wb[7] = f2b(b.w);
      } else {
        *(uint4*)wb = *(const uint4*)((const ushort_t*)e.w + e.woff + i);
      }
      unsigned mk = 0xFF;
      if (e.m) {
        mk = 0;
        if (mmode == 0) {
          const int4* mp = (const int4*)((const int*)e.m + e.moff + i);
          int4 a = mp[0], b = mp[1];
          mk = (a.x != 0) | ((a.y != 0) << 1) | ((a.z != 0) << 2) | ((a.w != 0) << 3) |
               ((b.x != 0) << 4) | ((b.y != 0) << 5) | ((b.z != 0) << 6) | ((b.w != 0) << 7);
        } else if (mmode == 1) {
          const uint2 mv = *(const uint2*)((const unsigned char*)e.m + e.moff + i);
          const unsigned char* mb = (const unsigned char*)&mv;
          for (int j = 0; j < 8; j++) mk |= (mb[j] != 0) << j;
        } else if (mmode == 2) {
          uint4 mv = *(const uint4*)((const ushort_t*)e.m + e.moff + i);
          const ushort_t* ms = (const ushort_t*)&mv;
          for (int j = 0; j < 8; j++) mk |= (ms[j] != 0) << j;
        } else {
          const uint4* mp = (const uint4*)((const unsigned int*)e.m + e.moff + i);
          uint4 a = mp[0], b = mp[1];
          const unsigned* u = (const unsigned*)&a;
          const unsigned* v = (const unsigned*)&b;
          for (int j = 0; j < 4; j++) mk |= (u[j] != 0) << j;
          for (int j = 0; j < 4; j++) mk |= (v[j] != 0) << (4 + j);
        }
      }
#pragma unroll
      for (int j = 0; j < 8; j++) o[j] = ((mk >> j) & 1) ? wb[j] : (ushort_t)0;
    }
    *(uint4*)(e.o + i) = *(uint4*)o;
  }
}

// ---------------- fused multi-source GEMM, barrier-light pipeline ----------------
// C[M,N] = sum_s relu(A_s[M,K] * B_s[N,K]^T + bias_s)
// grid = 256 blocks (BM=256 x BN=128 over M=8192, N_pad=1024), block = 512.
struct GemmSrc { const ushort_t* A; const ushort_t* B; const ushort_t* bias; };
struct GemmArgs { GemmSrc s[4]; };

#define SBAR()  asm volatile("s_barrier" ::: "memory")
#define LGKM0() asm volatile("s_waitcnt lgkmcnt(0)" ::: "memory")
#define VMC6()  asm volatile("s_waitcnt vmcnt(6)" ::: "memory")
#define VMC0()  asm volatile("s_waitcnt vmcnt(0)" ::: "memory")

template <int NSRC, bool RELU, bool NGUARD>
__launch_bounds__(512, 2)
__global__ void gemm_multi(GemmArgs args, void* Cv, const int* of32flag,
                           int K, int N_real, int ldc)
{
  // per buffer: A 256x64 bf16 (16384 el) + B 128x64 bf16 (8192 el) = 48KB
  __shared__ __align__(16) ushort_t lds[2][24576];

  const bool of32 = (of32flag != nullptr) && (of32flag[0] != 0);
  __hip_bfloat16* C = (__hip_bfloat16*)Cv;
  float* Cf = (float*)Cv;

  const int tid  = threadIdx.x;
  const int lane = tid & 63;
  const int wave = tid >> 6;
  const int wm = (wave >> 1) * 64;   // 0,64,128,192
  const int wn = (wave & 1) * 64;    // 0,64
  const int fr = lane & 15;
  const int kg = lane >> 4;

  // XCD-aware remap (grid=256, nwg%8==0 -> bijective): XCD x = lid&7 owns
  // M-panels 4x..4x+3, each paired with all 8 N-tiles -> A panel hits its
  // XCD L2 once; B (2MB/source) L2-resident.
  const int lid = blockIdx.x;
  const int xcd = lid & 7, chunk = lid >> 3;
  const int bm = (xcd * 4 + (chunk >> 3)) * 256;
  const int bn = (chunk & 7) * 128;

  // -------- staging addressing: linear LDS dest, inverse-swizzled source.
  // thread t writes LDS row rbase, 16B-slot (t&7); global slot sg = (t&7)^(rbase&7).
  const int rbase = tid >> 3;               // 0..63 per call
  const int sg    = (tid & 7) ^ (rbase & 7);
  const size_t aoff = (size_t)(bm + rbase) * K + sg * 8;
  const size_t boff = (size_t)(bn + rbase) * K + sg * 8;
  const size_t rs64 = (size_t)64 * K;

  auto stage = [&](const ushort_t* gA, const ushort_t* gB, int buf) {
    ushort_t* base = &lds[buf][0];
    ushort_t* lA = base + wave * 512;            // A at elem 0
    ushort_t* lB = base + 16384 + wave * 512;    // B at elem 16384
    gl_lds16(gA,            lA);
    gl_lds16(gA + rs64,     lA + 4096);
    gl_lds16(gA + 2 * rs64, lA + 8192);
    gl_lds16(gA + 3 * rs64, lA + 12288);
    gl_lds16(gB,            lB);
    gl_lds16(gB + rs64,     lB + 4096);
  };

  // -------- fragment read addressing (XOR-swizzled, slot = kg ^ (fr&7)) ----
  const int s0   = (kg ^ (fr & 7)) * 16;    // byte slot, ks=0; ks=1 -> ^64
  const int arow = (wm + fr) * 128;         // byte offset of A row
  const int brow = 32768 + (wn + fr) * 128; // byte offset of B row

  f32x4 acc[4][4], out_acc[4][4];
#pragma unroll
  for (int i = 0; i < 4; i++)
#pragma unroll
    for (int j = 0; j < 4; j++) {
      acc[i][j] = (f32x4){0.f, 0.f, 0.f, 0.f};
      if (NSRC > 1) out_acc[i][j] = (f32x4){0.f, 0.f, 0.f, 0.f};
    }

  // biases preloaded (keeps vmcnt accounting in the K-loop exact)
  float bpre[NSRC][4];
#pragma unroll
  for (int s = 0; s < NSRC; ++s)
#pragma unroll
    for (int ni = 0; ni < 4; ni++)
      bpre[s][ni] = (float)*(const __hip_bfloat16*)
          (args.s[s].bias + bn + wn + ni * 16 + fr);

  const int TPS = K >> 6;          // K-tiles per source (16 or 32)
  const int NT  = TPS * NSRC;

  // prologue: stage tiles 0,1; wait tile 0 (leave tile 1's 6 loads flying)
  stage(args.s[0].A + aoff, args.s[0].B + boff, 0);
  {
    const int s1 = 1 / TPS, k1 = (1 % TPS) * 64;
    stage(args.s[s1].A + aoff + k1, args.s[s1].B + boff + k1, 1);
  }
  VMC6();
  SBAR();

  int psrc = 2 / TPS, pk0 = (2 % TPS) * 64;  // next tile to stage
  int csrc = 0, ck = 0;
  int cur = 0;

  for (int t = 0; t < NT; ++t) {
    const char* Lb = (const char*)&lds[cur][0];

    // ---- one straight-line region: all 16 ds_read_b128 + all 32 MFMA.
    // Compiler schedules reads under MFMAs with fine-grained lgkmcnt
    // (m97-verified codegen) -> LDS read time hides under the matrix pipe.
    bf16x8 af[4][2], bfr[4][2];
#pragma unroll
    for (int m = 0; m < 4; ++m)
#pragma unroll
      for (int ks = 0; ks < 2; ++ks)
        af[m][ks] = *(const bf16x8*)(Lb + arow + m * 2048 + (s0 ^ (ks * 64)));
#pragma unroll
    for (int n = 0; n < 4; ++n)
#pragma unroll
      for (int ks = 0; ks < 2; ++ks)
        bfr[n][ks] = *(const bf16x8*)(Lb + brow + n * 2048 + (s0 ^ (ks * 64)));

    __builtin_amdgcn_s_setprio(1);
#pragma unroll
    for (int mi = 0; mi < 4; mi++)
#pragma unroll
      for (int ni = 0; ni < 4; ni++)
#pragma unroll
        for (int ks = 0; ks < 2; ++ks)
          acc[mi][ni] = __builtin_amdgcn_mfma_f32_16x16x32_bf16(
              af[mi][ks], bfr[ni][ks], acc[mi][ni], 0, 0, 0);
    __builtin_amdgcn_s_setprio(0);

    // ---- read-retirement fence: after this barrier, every wave's ds_reads
    // of buf `cur` are retired -> safe to overwrite with tile t+2.
    LGKM0();
    SBAR();

    ck += 64;
    const bool srcEnd = (ck == K);
    const bool more2 = (t + 2 < NT);
    if (more2) {
      stage(args.s[psrc].A + aoff + pk0, args.s[psrc].B + boff + pk0, cur);
      pk0 += 64; if (pk0 == K) { pk0 = 0; ++psrc; }
    }

    // source-boundary epilogue (VALU only; overlaps load flight)
    if (NSRC > 1 && srcEnd) {
      float bb[4];
#pragma unroll
      for (int s = 0; s < NSRC; ++s)
        if (s == csrc) {
#pragma unroll
          for (int ni = 0; ni < 4; ni++) bb[ni] = bpre[s][ni];
        }
#pragma unroll
      for (int ni = 0; ni < 4; ni++)
#pragma unroll
        for (int mi = 0; mi < 4; mi++)
#pragma unroll
          for (int j = 0; j < 4; j++) {
            float v = acc[mi][ni][j] + bb[ni];
            if (RELU) v = fmaxf(v, 0.0f);
            out_acc[mi][ni][j] += v;
            acc[mi][ni][j] = 0.0f;
          }
      ck = 0; ++csrc;
    }

    // ---- counted vmcnt: wait tile t+1's 6 loads (issued one full tile
    // ago); tile t+2's 6 stay in flight across the barrier. Never 0 until
    // the final tile's loads.
    if (t + 1 < NT) {
      if (more2) VMC6(); else VMC0();
      SBAR();
    }
    cur ^= 1;
  }

  // store: C/D layout col = lane&15, row = (lane>>4)*4 + reg  (verified R3)
#pragma unroll
  for (int ni = 0; ni < 4; ni++) {
    const int c = bn + wn + ni * 16 + fr;
    if (NGUARD && c >= N_real) continue;
#pragma unroll
    for (int mi = 0; mi < 4; mi++) {
      const int r0 = bm + wm + mi * 16 + kg * 4;
#pragma unroll
      for (int j = 0; j < 4; j++) {
        const size_t idx = (size_t)(r0 + j) * ldc + c;
        float v;
        if (NSRC == 1) {
          v = acc[mi][ni][j] + bpre[0][ni];
          if (RELU) v = fmaxf(v, 0.0f);
        } else {
          v = out_acc[mi][ni][j];
        }
        if (of32) Cf[idx] = v;
        else      C[idx]  = (__hip_bfloat16)v;
      }
    }
  }
}

extern "C" void kernel_launch(void* const* d_in, const int* in_sizes, int n_in,
                              void* d_out, int out_size, void* d_ws, size_t ws_size,
                              hipStream_t stream) {
  (void)out_size; (void)ws_size;
  const int Bm = 8192, DIN = 2048, H = 1024, Cn = 1000;
  const size_t HH = (size_t)H * H;

  // ---- size-signature input resolver (verified R3) ----
  struct PO { const void* p; size_t off; };
  PO x{d_in[0], 0}, Wf{d_in[0], 0}, mf{d_in[0], 0}, Wo{d_in[0], 0}, mo{d_in[0], 0};
  PO bf{d_in[0], 0}, bo{d_in[0], 0};
  PO mW[4], mM[4], mB[4], sW[6], sM[6], sB[6];
  for (int i = 0; i < 4; i++) { mW[i] = {d_in[0], 0}; mM[i] = mW[i]; mB[i] = mW[i]; }
  for (int i = 0; i < 6; i++) { sW[i] = {d_in[0], 0}; sM[i] = sW[i]; sB[i] = sW[i]; }

  {
    int c2M = 0, c1M = 0, c1k = 0, cWoMo = 0, c4 = 0, c6 = 0;
    for (int i = 0; i < n_in; i++) {
      const int s = in_sizes[i];
      const void* p = d_in[i];
      switch (s) {
        case 16777216: x = {p, 0}; break;
        case 2097152:  if (c2M++ == 0) Wf = {p, 0}; else mf = {p, 0}; break;
        case 1048576: {
          int j = c1M++;
          if (j < 4)       mW[j]      = {p, 0};
          else if (j < 8)  mM[j - 4]  = {p, 0};
          else if (j < 14) sW[j - 8]  = {p, 0};
          else if (j < 20) sM[j - 14] = {p, 0};
          break;
        }
        case 1024: {
          int j = c1k++;
          if (j == 0)      bf        = {p, 0};
          else if (j < 5)  mB[j - 1] = {p, 0};
          else if (j < 11) sB[j - 5] = {p, 0};
          break;
        }
        case 1024000: if (cWoMo++ == 0) Wo = {p, 0}; else mo = {p, 0}; break;
        case 1000: bo = {p, 0}; break;
        case 4194304:
          for (int t = 0; t < 4; t++) {
            if (c4 == 0) mW[t] = {p, t * HH}; else mM[t] = {p, t * HH};
          }
          c4++; break;
        case 6291456:
          for (int t = 0; t < 6; t++) {
            if (c6 == 0) sW[t] = {p, t * HH}; else sM[t] = {p, t * HH};
          }
          c6++; break;
        case 4096:
          for (int t = 0; t < 4; t++) mB[t] = {p, (size_t)t * H};
          break;
        case 6144:
          for (int t = 0; t < 6; t++) sB[t] = {p, (size_t)t * H};
          break;
        default: break;
      }
    }
  }

  // ---- workspace layout (ushort units) ----
  ushort_t* wsp = (ushort_t*)d_ws;
  size_t off = 0;
  int* flags = (int*)wsp; off += 32;
  ushort_t* xc = wsp + off; off += (size_t)Bm * DIN;
  __hip_bfloat16* r[5];
  for (int i = 0; i < 5; i++) { r[i] = (__hip_bfloat16*)(wsp + off); off += (size_t)Bm * H; }
  ushort_t* wWf = wsp + off; off += (size_t)H * DIN;
  ushort_t* wMain[4];
  for (int i = 0; i < 4; i++) { wMain[i] = wsp + off; off += HH; }
  ushort_t* wSkip[6];
  for (int k = 0; k < 6; k++) { wSkip[k] = wsp + off; off += HH; }
  ushort_t* wWo = wsp + off; off += (size_t)1024 * 1024;  // zero-padded to 1024 rows
  ushort_t* cbf_ = wsp + off; off += 1024;
  ushort_t* cmB[4];
  for (int i = 0; i < 4; i++) { cmB[i] = wsp + off; off += 1024; }
  ushort_t* csB[6];
  for (int k = 0; k < 6; k++) { csB[k] = wsp + off; off += 1024; }
  ushort_t* cbo = wsp + off; off += 1024;                 // tail 1000..1023 zeroed

  // ---- launches ----
  detect_kernel<<<1, 256, 0, stream>>>((const ushort_t*)x.p, (const ushort_t*)mf.p, flags);

  PrepAll p;
  p.e[0]  = { Wf.p, Wf.off, mf.p, mf.off, wWf, H * DIN, H * DIN };
  for (int i = 0; i < 4; i++)
    p.e[1 + i] = { mW[i].p, mW[i].off, mM[i].p, mM[i].off, wMain[i], (int)HH, (int)HH };
  for (int k = 0; k < 6; k++)
    p.e[5 + k] = { sW[k].p, sW[k].off, sM[k].p, sM[k].off, wSkip[k], (int)HH, (int)HH };
  p.e[11] = { Wo.p, Wo.off, mo.p, mo.off, wWo, 1024 * 1024, Cn * H };
  p.e[12] = { bf.p, bf.off, nullptr, 0, cbf_, H, H };
  for (int i = 0; i < 4; i++)
    p.e[13 + i] = { mB[i].p, mB[i].off, nullptr, 0, cmB[i], H, H };
  for (int k = 0; k < 6; k++)
    p.e[17 + k] = { sB[k].p, sB[k].off, nullptr, 0, csB[k], H, H };
  p.e[23] = { bo.p, bo.off, nullptr, 0, cbo, 1024, Cn };
  p.e[24] = { x.p, x.off, nullptr, 0, xc, Bm * DIN, Bm * DIN };   // x conversion
  prep_weights<<<dim3(256, 25), dim3(256), 0, stream>>>(p, flags);

  const dim3 g(256), b(512);

  GemmArgs a0; a0.s[0] = { xc, wWf, cbf_ };
  gemm_multi<1, true, false><<<g, b, 0, stream>>>(a0, r[0], nullptr, DIN, H, H);

  GemmArgs a1; a1.s[0] = { (ushort_t*)r[0], wMain[0], cmB[0] };
  gemm_multi<1, true, false><<<g, b, 0, stream>>>(a1, r[1], nullptr, H, H, H);

  GemmArgs a2;
  a2.s[0] = { (ushort_t*)r[1], wMain[1], cmB[1] };
  a2.s[1] = { (ushort_t*)r[0], wSkip[0], csB[0] };
  gemm_multi<2, true, false><<<g, b, 0, stream>>>(a2, r[2], nullptr, H, H, H);

  GemmArgs a3;
  a3.s[0] = { (ushort_t*)r[2], wMain[2], cmB[2] };
  a3.s[1] = { (ushort_t*)r[0], wSkip[1], csB[1] };
  a3.s[2] = { (ushort_t*)r[1], wSkip[2], csB[2] };
  gemm_multi<3, true, false><<<g, b, 0, stream>>>(a3, r[3], nullptr, H, H, H);

  GemmArgs a4;
  a4.s[0] = { (ushort_t*)r[3], wMain[3], cmB[3] };
  a4.s[1] = { (ushort_t*)r[0], wSkip[3], csB[3] };
  a4.s[2] = { (ushort_t*)r[1], wSkip[4], csB[4] };
  a4.s[3] = { (ushort_t*)r[2], wSkip[5], csB[5] };
  gemm_multi<4, true, false><<<g, b, 0, stream>>>(a4, r[4], nullptr, H, H, H);

  GemmArgs ao; ao.s[0] = { (ushort_t*)r[4], wWo, cbo };
  gemm_multi<1, false, true><<<g, b, 0, stream>>>(ao, d_out, flags, H, Cn, Cn);
}

// Round 3
// 529.828 us; speedup vs baseline: 1.0544x; 1.0104x over previous
//
#include <hip/hip_runtime.h>
#include <hip/hip_bf16.h>
#include <stdint.h>

// MaskedDeepDAN on MI355X (gfx950). B=8192, D_IN=2048, H=1024, C=1000.
// R9: R8's accounting closed at per-tile 3731 cyc = SERIAL sum of LDS pipe
// (~1900) + matrix pipe (~1242) + sync (~500): waves in lockstep do
// read-burst then MFMA-burst, pipes alternate instead of overlap. Fix:
// software-pipeline fragments by one half-tile (ks slice). Two named frag
// sets; each ds_read burst is issued immediately before a 16-MFMA block
// that does NOT consume it:
//   read ks1 -> MFMA(ks0) ; lgkm0+bar ; stage(t+2) ; vmcnt6+bar ;
//   read ks0(t+1, other buf) -> MFMA(ks1)
// sched_barrier(0) pins each read-burst above its covering MFMA block.
// Compiler inserts precise counted lgkm waits for the C++ LDS loads
// (m97-verified codegen). Structural waits kept from R8: lgkm0 before the
// staging barrier (cross-wave retirement), counted vmcnt(6) (never 0 in
// main loop). Geometry/swizzle/XCD-remap/staging/epilogue/prep unchanged.

typedef unsigned short ushort_t;
typedef __bf16 bf16x8 __attribute__((ext_vector_type(8)));
typedef float f32x4 __attribute__((ext_vector_type(4)));

__device__ __forceinline__ void gl_lds16(const void* g, void* l) {
  typedef __attribute__((address_space(1))) void gvoid;
  typedef __attribute__((address_space(3))) void lvoid;
  __builtin_amdgcn_global_load_lds((gvoid*)(void*)g, (lvoid*)l, 16, 0, 0);
}

__device__ __forceinline__ ushort_t f2b(float f) {
  __hip_bfloat16 h = (__hip_bfloat16)f;
  return *(ushort_t*)&h;
}

// ---------------- dtype detection (verified R3) ----------------
// flags[0] = 1 if floats are fp32, 0 if bf16
// flags[1] = mask mode: 0=int32, 1=uint8, 2=bf16(u16), 3=fp32
__global__ void detect_kernel(const ushort_t* x, const ushort_t* mf, int* flags) {
  __shared__ int s[4];
  if (threadIdx.x < 4) s[threadIdx.x] = 0;
  __syncthreads();
  int expout = 0, m3f80_even = 0, m3f80_odd = 0, mhi01 = 0;
  for (int k = threadIdx.x; k < 2048; k += 256) {
    ushort_t w = x[k];
    int e = (w >> 7) & 0xFF;
    if (e < 96 || e > 144) expout++;
    ushort_t mw = mf[k];
    if (mw == 0x3F80) { if (k & 1) m3f80_odd++; else m3f80_even++; }
    if ((mw >> 8) == 1) mhi01++;
  }
  atomicAdd(&s[0], expout);
  atomicAdd(&s[1], m3f80_even);
  atomicAdd(&s[2], m3f80_odd);
  atomicAdd(&s[3], mhi01);
  __syncthreads();
  if (threadIdx.x == 0) {
    flags[0] = (s[0] > 100) ? 1 : 0;
    int mmode = 0;
    if (s[1] > 100) mmode = 2;
    else if (s[2] > 100) mmode = 3;
    else if (s[3] > 200) mmode = 1;
    flags[1] = mmode;
  }
}

// -------- masking + dtype conversion (weights, biases, and x) --------
struct PrepEnt {
  const void* w; size_t woff;
  const void* m; size_t moff;   // nullptr -> no mask
  ushort_t* o;
  int n;
  int valid;                    // i >= valid -> 0
};
struct PrepAll { PrepEnt e[25]; };

__global__ void prep_weights(PrepAll p, const int* flags) {
  const bool f32 = flags[0] != 0;
  const int mmode = flags[1];
  const PrepEnt e = p.e[blockIdx.y];
  const int nch = e.n >> 3;
  const int stride = blockDim.x * gridDim.x;
  for (int ci = blockIdx.x * blockDim.x + threadIdx.x; ci < nch; ci += stride) {
    const int i = ci << 3;
    ushort_t o[8] = {0, 0, 0, 0, 0, 0, 0, 0};
    if (i < e.valid) {
      ushort_t wb[8];
      if (f32) {
        const float* wp = (const float*)e.w + e.woff + i;
        float4 a = *(const float4*)wp;
        float4 b = *(const float4*)(wp + 4);
        wb[0] = f2b(a.x); wb[1] = f2b(a.y); wb[2] = f2b(a.z); wb[3] = f2b(a.w);
        wb[4] = f2b(b.x); wb[5] = f2b(b.y); wb[6] = f2b(b.z); wb[7] = f2b(b.w);
      } else {
        *(uint4*)wb = *(const uint4*)((const ushort_t*)e.w + e.woff + i);
      }
      unsigned mk = 0xFF;
      if (e.m) {
        mk = 0;
        if (mmode == 0) {
          const int4* mp = (const int4*)((const int*)e.m + e.moff + i);
          int4 a = mp[0], b = mp[1];
          mk = (a.x != 0) | ((a.y != 0) << 1) | ((a.z != 0) << 2) | ((a.w != 0) << 3) |
               ((b.x != 0) << 4) | ((b.y != 0) << 5) | ((b.z != 0) << 6) | ((b.w != 0) << 7);
        } else if (mmode == 1) {
          const uint2 mv = *(const uint2*)((const unsigned char*)e.m + e.moff + i);
          const unsigned char* mb = (const unsigned char*)&mv;
          for (int j = 0; j < 8; j++) mk |= (mb[j] != 0) << j;
        } else if (mmode == 2) {
          uint4 mv = *(const uint4*)((const ushort_t*)e.m + e.moff + i);
          const ushort_t* ms = (const ushort_t*)&mv;
          for (int j = 0; j < 8; j++) mk |= (ms[j] != 0) << j;
        } else {
          const uint4* mp = (const uint4*)((const unsigned int*)e.m + e.moff + i);
          uint4 a = mp[0], b = mp[1];
          const unsigned* u = (const unsigned*)&a;
          const unsigned* v = (const unsigned*)&b;
          for (int j = 0; j < 4; j++) mk |= (u[j] != 0) << j;
          for (int j = 0; j < 4; j++) mk |= (v[j] != 0) << (4 + j);
        }
      }
#pragma unroll
      for (int j = 0; j < 8; j++) o[j] = ((mk >> j) & 1) ? wb[j] : (ushort_t)0;
    }
    *(uint4*)(e.o + i) = *(uint4*)o;
  }
}

// ---------------- fused multi-source GEMM, half-tile-pipelined ----------------
// C[M,N] = sum_s relu(A_s[M,K] * B_s[N,K]^T + bias_s)
// grid = 256 blocks (BM=256 x BN=128 over M=8192, N_pad=1024), block = 512.
struct GemmSrc { const ushort_t* A; const ushort_t* B; const ushort_t* bias; };
struct GemmArgs { GemmSrc s[4]; };

#define SBAR()  asm volatile("s_barrier" ::: "memory")
#define LGKM0() asm volatile("s_waitcnt lgkmcnt(0)" ::: "memory")
#define VMC6()  asm volatile("s_waitcnt vmcnt(6)" ::: "memory")
#define VMC0()  asm volatile("s_waitcnt vmcnt(0)" ::: "memory")

template <int NSRC, bool RELU, bool NGUARD>
__launch_bounds__(512, 2)
__global__ void gemm_multi(GemmArgs args, void* Cv, const int* of32flag,
                           int K, int N_real, int ldc)
{
  // per buffer: A 256x64 bf16 (16384 el) + B 128x64 bf16 (8192 el) = 48KB
  __shared__ __align__(16) ushort_t lds[2][24576];

  const bool of32 = (of32flag != nullptr) && (of32flag[0] != 0);
  __hip_bfloat16* C = (__hip_bfloat16*)Cv;
  float* Cf = (float*)Cv;

  const int tid  = threadIdx.x;
  const int lane = tid & 63;
  const int wave = tid >> 6;
  const int wm = (wave >> 1) * 64;   // 0,64,128,192
  const int wn = (wave & 1) * 64;    // 0,64
  const int fr = lane & 15;
  const int kg = lane >> 4;

  // XCD-aware remap (grid=256, nwg%8==0 -> bijective): XCD x = lid&7 owns
  // M-panels 4x..4x+3, each paired with all 8 N-tiles -> A panel hits its
  // XCD L2 once; B (2MB/source) L2-resident.
  const int lid = blockIdx.x;
  const int xcd = lid & 7, chunk = lid >> 3;
  const int bm = (xcd * 4 + (chunk >> 3)) * 256;
  const int bn = (chunk & 7) * 128;

  // -------- staging addressing: linear LDS dest, inverse-swizzled source.
  // thread t writes LDS row rbase, 16B-slot (t&7); global slot sg = (t&7)^(rbase&7).
  const int rbase = tid >> 3;               // 0..63 per call
  const int sg    = (tid & 7) ^ (rbase & 7);
  const size_t aoff = (size_t)(bm + rbase) * K + sg * 8;
  const size_t boff = (size_t)(bn + rbase) * K + sg * 8;
  const size_t rs64 = (size_t)64 * K;

  auto stage = [&](const ushort_t* gA, const ushort_t* gB, int buf) {
    ushort_t* base = &lds[buf][0];
    ushort_t* lA = base + wave * 512;            // A at elem 0
    ushort_t* lB = base + 16384 + wave * 512;    // B at elem 16384
    gl_lds16(gA,            lA);
    gl_lds16(gA + rs64,     lA + 4096);
    gl_lds16(gA + 2 * rs64, lA + 8192);
    gl_lds16(gA + 3 * rs64, lA + 12288);
    gl_lds16(gB,            lB);
    gl_lds16(gB + rs64,     lB + 4096);
  };

  // -------- fragment read addressing (XOR-swizzled, slot = kg ^ (fr&7)) ----
  const int s0   = (kg ^ (fr & 7)) * 16;    // byte slot, ks=0; ks=1 -> ^64
  const int arow = (wm + fr) * 128;         // byte offset of A row
  const int brow = 32768 + (wn + fr) * 128; // byte offset of B row

  f32x4 acc[4][4], out_acc[4][4];
#pragma unroll
  for (int i = 0; i < 4; i++)
#pragma unroll
    for (int j = 0; j < 4; j++) {
      acc[i][j] = (f32x4){0.f, 0.f, 0.f, 0.f};
      if (NSRC > 1) out_acc[i][j] = (f32x4){0.f, 0.f, 0.f, 0.f};
    }

  // biases preloaded (keeps vmcnt accounting in the K-loop exact)
  float bpre[NSRC][4];
#pragma unroll
  for (int s = 0; s < NSRC; ++s)
#pragma unroll
    for (int ni = 0; ni < 4; ni++)
      bpre[s][ni] = (float)*(const __hip_bfloat16*)
          (args.s[s].bias + bn + wn + ni * 16 + fr);

  const int TPS = K >> 6;          // K-tiles per source (16 or 32)
  const int NT  = TPS * NSRC;

  // two named fragment sets (static indexing, rule: no runtime-indexed regs)
  bf16x8 af0[4], bf0[4], af1[4], bf1[4];

  auto rdfrag0 = [&](const char* Lb, int ks) {
    const int so = s0 ^ (ks * 64);
#pragma unroll
    for (int m = 0; m < 4; ++m) af0[m] = *(const bf16x8*)(Lb + arow + m * 2048 + so);
#pragma unroll
    for (int n = 0; n < 4; ++n) bf0[n] = *(const bf16x8*)(Lb + brow + n * 2048 + so);
  };
  auto rdfrag1 = [&](const char* Lb, int ks) {
    const int so = s0 ^ (ks * 64);
#pragma unroll
    for (int m = 0; m < 4; ++m) af1[m] = *(const bf16x8*)(Lb + arow + m * 2048 + so);
#pragma unroll
    for (int n = 0; n < 4; ++n) bf1[n] = *(const bf16x8*)(Lb + brow + n * 2048 + so);
  };
  auto mfma16_0 = [&]() {
    __builtin_amdgcn_s_setprio(1);
#pragma unroll
    for (int mi = 0; mi < 4; mi++)
#pragma unroll
      for (int ni = 0; ni < 4; ni++)
        acc[mi][ni] = __builtin_amdgcn_mfma_f32_16x16x32_bf16(
            af0[mi], bf0[ni], acc[mi][ni], 0, 0, 0);
    __builtin_amdgcn_s_setprio(0);
  };
  auto mfma16_1 = [&]() {
    __builtin_amdgcn_s_setprio(1);
#pragma unroll
    for (int mi = 0; mi < 4; mi++)
#pragma unroll
      for (int ni = 0; ni < 4; ni++)
        acc[mi][ni] = __builtin_amdgcn_mfma_f32_16x16x32_bf16(
            af1[mi], bf1[ni], acc[mi][ni], 0, 0, 0);
    __builtin_amdgcn_s_setprio(0);
  };

  // prologue: stage tiles 0,1; wait tile 0 (leave tile 1's 6 loads flying);
  // pre-read ks=0 fragments of tile 0.
  stage(args.s[0].A + aoff, args.s[0].B + boff, 0);
  {
    const int s1 = 1 / TPS, k1 = (1 % TPS) * 64;
    stage(args.s[s1].A + aoff + k1, args.s[s1].B + boff + k1, 1);
  }
  VMC6();
  SBAR();
  rdfrag0((const char*)&lds[0][0], 0);

  int psrc = 2 / TPS, pk0 = (2 % TPS) * 64;  // next tile to stage
  int csrc = 0, ck = 0;
  int cur = 0;

  for (int t = 0; t < NT; ++t) {
    const char* Lb = (const char*)&lds[cur][0];

    // ---- read ks=1 frags (this tile), covered by MFMA on ks=0 frags ----
    rdfrag1(Lb, 1);
    __builtin_amdgcn_sched_barrier(0);   // pin reads above the MFMA block
    mfma16_0();                          // compiler inserts counted lgkm wait

    // ---- read-retirement fence: all waves' ds_reads of buf cur retired ->
    // safe to overwrite with tile t+2. (ks1 reads had a full MFMA block to
    // land; lgkm0 is near-free.)
    LGKM0();
    SBAR();

    ck += 64;
    const bool srcEnd = (ck == K);
    const bool more2 = (t + 2 < NT);
    if (more2) {
      stage(args.s[psrc].A + aoff + pk0, args.s[psrc].B + boff + pk0, cur);
      pk0 += 64; if (pk0 == K) { pk0 = 0; ++psrc; }
    }

    // ---- counted vmcnt: tile t+1's 6 loads (issued one full tile ago);
    // tile t+2's 6 stay in flight across the barrier. ----
    if (t + 1 < NT) {
      if (more2) VMC6(); else VMC0();
      SBAR();
      // read ks=0 frags of tile t+1 (other buffer), covered by MFMA(ks=1)
      rdfrag0((const char*)&lds[cur ^ 1][0], 0);
    }
    __builtin_amdgcn_sched_barrier(0);   // pin reads above the MFMA block
    mfma16_1();

    // source-boundary epilogue (acc complete only after the ks=1 block)
    if (NSRC > 1 && srcEnd) {
      float bb[4];
#pragma unroll
      for (int s = 0; s < NSRC; ++s)
        if (s == csrc) {
#pragma unroll
          for (int ni = 0; ni < 4; ni++) bb[ni] = bpre[s][ni];
        }
#pragma unroll
      for (int ni = 0; ni < 4; ni++)
#pragma unroll
        for (int mi = 0; mi < 4; mi++)
#pragma unroll
          for (int j = 0; j < 4; j++) {
            float v = acc[mi][ni][j] + bb[ni];
            if (RELU) v = fmaxf(v, 0.0f);
            out_acc[mi][ni][j] += v;
            acc[mi][ni][j] = 0.0f;
          }
      ck = 0; ++csrc;
    }

    cur ^= 1;
  }

  // store: C/D layout col = lane&15, row = (lane>>4)*4 + reg  (verified R3)
#pragma unroll
  for (int ni = 0; ni < 4; ni++) {
    const int c = bn + wn + ni * 16 + fr;
    if (NGUARD && c >= N_real) continue;
#pragma unroll
    for (int mi = 0; mi < 4; mi++) {
      const int r0 = bm + wm + mi * 16 + kg * 4;
#pragma unroll
      for (int j = 0; j < 4; j++) {
        const size_t idx = (size_t)(r0 + j) * ldc + c;
        float v;
        if (NSRC == 1) {
          v = acc[mi][ni][j] + bpre[0][ni];
          if (RELU) v = fmaxf(v, 0.0f);
        } else {
          v = out_acc[mi][ni][j];
        }
        if (of32) Cf[idx] = v;
        else      C[idx]  = (__hip_bfloat16)v;
      }
    }
  }
}

extern "C" void kernel_launch(void* const* d_in, const int* in_sizes, int n_in,
                              void* d_out, int out_size, void* d_ws, size_t ws_size,
                              hipStream_t stream) {
  (void)out_size; (void)ws_size;
  const int Bm = 8192, DIN = 2048, H = 1024, Cn = 1000;
  const size_t HH = (size_t)H * H;

  // ---- size-signature input resolver (verified R3) ----
  struct PO { const void* p; size_t off; };
  PO x{d_in[0], 0}, Wf{d_in[0], 0}, mf{d_in[0], 0}, Wo{d_in[0], 0}, mo{d_in[0], 0};
  PO bf{d_in[0], 0}, bo{d_in[0], 0};
  PO mW[4], mM[4], mB[4], sW[6], sM[6], sB[6];
  for (int i = 0; i < 4; i++) { mW[i] = {d_in[0], 0}; mM[i] = mW[i]; mB[i] = mW[i]; }
  for (int i = 0; i < 6; i++) { sW[i] = {d_in[0], 0}; sM[i] = sW[i]; sB[i] = sW[i]; }

  {
    int c2M = 0, c1M = 0, c1k = 0, cWoMo = 0, c4 = 0, c6 = 0;
    for (int i = 0; i < n_in; i++) {
      const int s = in_sizes[i];
      const void* p = d_in[i];
      switch (s) {
        case 16777216: x = {p, 0}; break;
        case 2097152:  if (c2M++ == 0) Wf = {p, 0}; else mf = {p, 0}; break;
        case 1048576: {
          int j = c1M++;
          if (j < 4)       mW[j]      = {p, 0};
          else if (j < 8)  mM[j - 4]  = {p, 0};
          else if (j < 14) sW[j - 8]  = {p, 0};
          else if (j < 20) sM[j - 14] = {p, 0};
          break;
        }
        case 1024: {
          int j = c1k++;
          if (j == 0)      bf        = {p, 0};
          else if (j < 5)  mB[j - 1] = {p, 0};
          else if (j < 11) sB[j - 5] = {p, 0};
          break;
        }
        case 1024000: if (cWoMo++ == 0) Wo = {p, 0}; else mo = {p, 0}; break;
        case 1000: bo = {p, 0}; break;
        case 4194304:
          for (int t = 0; t < 4; t++) {
            if (c4 == 0) mW[t] = {p, t * HH}; else mM[t] = {p, t * HH};
          }
          c4++; break;
        case 6291456:
          for (int t = 0; t < 6; t++) {
            if (c6 == 0) sW[t] = {p, t * HH}; else sM[t] = {p, t * HH};
          }
          c6++; break;
        case 4096:
          for (int t = 0; t < 4; t++) mB[t] = {p, (size_t)t * H};
          break;
        case 6144:
          for (int t = 0; t < 6; t++) sB[t] = {p, (size_t)t * H};
          break;
        default: break;
      }
    }
  }

  // ---- workspace layout (ushort units) ----
  ushort_t* wsp = (ushort_t*)d_ws;
  size_t off = 0;
  int* flags = (int*)wsp; off += 32;
  ushort_t* xc = wsp + off; off += (size_t)Bm * DIN;
  __hip_bfloat16* r[5];
  for (int i = 0; i < 5; i++) { r[i] = (__hip_bfloat16*)(wsp + off); off += (size_t)Bm * H; }
  ushort_t* wWf = wsp + off; off += (size_t)H * DIN;
  ushort_t* wMain[4];
  for (int i = 0; i < 4; i++) { wMain[i] = wsp + off; off += HH; }
  ushort_t* wSkip[6];
  for (int k = 0; k < 6; k++) { wSkip[k] = wsp + off; off += HH; }
  ushort_t* wWo = wsp + off; off += (size_t)1024 * 1024;  // zero-padded to 1024 rows
  ushort_t* cbf_ = wsp + off; off += 1024;
  ushort_t* cmB[4];
  for (int i = 0; i < 4; i++) { cmB[i] = wsp + off; off += 1024; }
  ushort_t* csB[6];
  for (int k = 0; k < 6; k++) { csB[k] = wsp + off; off += 1024; }
  ushort_t* cbo = wsp + off; off += 1024;                 // tail 1000..1023 zeroed

  // ---- launches ----
  detect_kernel<<<1, 256, 0, stream>>>((const ushort_t*)x.p, (const ushort_t*)mf.p, flags);

  PrepAll p;
  p.e[0]  = { Wf.p, Wf.off, mf.p, mf.off, wWf, H * DIN, H * DIN };
  for (int i = 0; i < 4; i++)
    p.e[1 + i] = { mW[i].p, mW[i].off, mM[i].p, mM[i].off, wMain[i], (int)HH, (int)HH };
  for (int k = 0; k < 6; k++)
    p.e[5 + k] = { sW[k].p, sW[k].off, sM[k].p, sM[k].off, wSkip[k], (int)HH, (int)HH };
  p.e[11] = { Wo.p, Wo.off, mo.p, mo.off, wWo, 1024 * 1024, Cn * H };
  p.e[12] = { bf.p, bf.off, nullptr, 0, cbf_, H, H };
  for (int i = 0; i < 4; i++)
    p.e[13 + i] = { mB[i].p, mB[i].off, nullptr, 0, cmB[i], H, H };
  for (int k = 0; k < 6; k++)
    p.e[17 + k] = { sB[k].p, sB[k].off, nullptr, 0, csB[k], H, H };
  p.e[23] = { bo.p, bo.off, nullptr, 0, cbo, 1024, Cn };
  p.e[24] = { x.p, x.off, nullptr, 0, xc, Bm * DIN, Bm * DIN };   // x conversion
  prep_weights<<<dim3(256, 25), dim3(256), 0, stream>>>(p, flags);

  const dim3 g(256), b(512);

  GemmArgs a0; a0.s[0] = { xc, wWf, cbf_ };
  gemm_multi<1, true, false><<<g, b, 0, stream>>>(a0, r[0], nullptr, DIN, H, H);

  GemmArgs a1; a1.s[0] = { (ushort_t*)r[0], wMain[0], cmB[0] };
  gemm_multi<1, true, false><<<g, b, 0, stream>>>(a1, r[1], nullptr, H, H, H);

  GemmArgs a2;
  a2.s[0] = { (ushort_t*)r[1], wMain[1], cmB[1] };
  a2.s[1] = { (ushort_t*)r[0], wSkip[0], csB[0] };
  gemm_multi<2, true, false><<<g, b, 0, stream>>>(a2, r[2], nullptr, H, H, H);

  GemmArgs a3;
  a3.s[0] = { (ushort_t*)r[2], wMain[2], cmB[2] };
  a3.s[1] = { (ushort_t*)r[0], wSkip[1], csB[1] };
  a3.s[2] = { (ushort_t*)r[1], wSkip[2], csB[2] };
  gemm_multi<3, true, false><<<g, b, 0, stream>>>(a3, r[3], nullptr, H, H, H);

  GemmArgs a4;
  a4.s[0] = { (ushort_t*)r[3], wMain[3], cmB[3] };
  a4.s[1] = { (ushort_t*)r[0], wSkip[3], csB[3] };
  a4.s[2] = { (ushort_t*)r[1], wSkip[4], csB[4] };
  a4.s[3] = { (ushort_t*)r[2], wSkip[5], csB[5] };
  gemm_multi<4, true, false><<<g, b, 0, stream>>>(a4, r[4], nullptr, H, H, H);

  GemmArgs ao; ao.s[0] = { (ushort_t*)r[4], wWo, cbo };
  gemm_multi<1, false, true><<<g, b, 0, stream>>>(ao, d_out, flags, H, Cn, Cn);
}

// Round 4
// 515.182 us; speedup vs baseline: 1.0843x; 1.0284x over previous
//
#include <hip/hip_runtime.h>
#include <hip/hip_bf16.h>
#include <stdint.h>

// MaskedDeepDAN on MI355X (gfx950). B=8192, D_IN=2048, H=1024, C=1000.
// R10: R7-R9 all landed ~3600 cyc/tile vs the 1242-cyc matrix-pipe floor
// (MfmaUtil 26-29%) regardless of schedule. Shared invariant: 1 block/CU ->
// all 8 waves in ONE barrier group -> whole CU in lockstep, staging/LDS/
// barrier time serializes with MFMA. m97's 874 TF (3 indep blocks/CU) and
// R6's 583 (2 blocks/CU) scale EXACTLY with resident independent blocks.
// Fix: halve the block. BM=128 x BN=128 x BK=64, 256 thr / 4 waves
// (2Mx2N, 64x64/wave - per-wave code identical to R9), LDS 2x32KB = 64KB
// -> 2 independent blocks/CU (grid 64x8 = 512). Block A's barriers/vmcnt
// stalls now hide under block B's MFMA bursts (m114 co-scheduling).
// Staging: 8 x gl_lds16 per thread per tile; steady-state vmcnt(8).
// Schedule carried from R9: half-tile pipelined frags, 2 barriers/tile,
// counted vmcnt never 0 in main loop, lgkm0 read-retirement fence,
// XOR-swizzled staging/reads (bank-conflict 0, verified R7-R9).
// Prep/detect/resolver/epilogue/store verified R3-R9.

typedef unsigned short ushort_t;
typedef __bf16 bf16x8 __attribute__((ext_vector_type(8)));
typedef float f32x4 __attribute__((ext_vector_type(4)));

__device__ __forceinline__ void gl_lds16(const void* g, void* l) {
  typedef __attribute__((address_space(1))) void gvoid;
  typedef __attribute__((address_space(3))) void lvoid;
  __builtin_amdgcn_global_load_lds((gvoid*)(void*)g, (lvoid*)l, 16, 0, 0);
}

__device__ __forceinline__ ushort_t f2b(float f) {
  __hip_bfloat16 h = (__hip_bfloat16)f;
  return *(ushort_t*)&h;
}

// ---------------- dtype detection (verified R3) ----------------
// flags[0] = 1 if floats are fp32, 0 if bf16
// flags[1] = mask mode: 0=int32, 1=uint8, 2=bf16(u16), 3=fp32
__global__ void detect_kernel(const ushort_t* x, const ushort_t* mf, int* flags) {
  __shared__ int s[4];
  if (threadIdx.x < 4) s[threadIdx.x] = 0;
  __syncthreads();
  int expout = 0, m3f80_even = 0, m3f80_odd = 0, mhi01 = 0;
  for (int k = threadIdx.x; k < 2048; k += 256) {
    ushort_t w = x[k];
    int e = (w >> 7) & 0xFF;
    if (e < 96 || e > 144) expout++;
    ushort_t mw = mf[k];
    if (mw == 0x3F80) { if (k & 1) m3f80_odd++; else m3f80_even++; }
    if ((mw >> 8) == 1) mhi01++;
  }
  atomicAdd(&s[0], expout);
  atomicAdd(&s[1], m3f80_even);
  atomicAdd(&s[2], m3f80_odd);
  atomicAdd(&s[3], mhi01);
  __syncthreads();
  if (threadIdx.x == 0) {
    flags[0] = (s[0] > 100) ? 1 : 0;
    int mmode = 0;
    if (s[1] > 100) mmode = 2;
    else if (s[2] > 100) mmode = 3;
    else if (s[3] > 200) mmode = 1;
    flags[1] = mmode;
  }
}

// -------- masking + dtype conversion (weights, biases, and x) --------
struct PrepEnt {
  const void* w; size_t woff;
  const void* m; size_t moff;   // nullptr -> no mask
  ushort_t* o;
  int n;
  int valid;                    // i >= valid -> 0
};
struct PrepAll { PrepEnt e[25]; };

__global__ void prep_weights(PrepAll p, const int* flags) {
  const bool f32 = flags[0] != 0;
  const int mmode = flags[1];
  const PrepEnt e = p.e[blockIdx.y];
  const int nch = e.n >> 3;
  const int stride = blockDim.x * gridDim.x;
  for (int ci = blockIdx.x * blockDim.x + threadIdx.x; ci < nch; ci += stride) {
    const int i = ci << 3;
    ushort_t o[8] = {0, 0, 0, 0, 0, 0, 0, 0};
    if (i < e.valid) {
      ushort_t wb[8];
      if (f32) {
        const float* wp = (const float*)e.w + e.woff + i;
        float4 a = *(const float4*)wp;
        float4 b = *(const float4*)(wp + 4);
        wb[0] = f2b(a.x); wb[1] = f2b(a.y); wb[2] = f2b(a.z); wb[3] = f2b(a.w);
        wb[4] = f2b(b.x); wb[5] = f2b(b.y); wb[6] = f2b(b.z); wb[7] = f2b(b.w);
      } else {
        *(uint4*)wb = *(const uint4*)((const ushort_t*)e.w + e.woff + i);
      }
      unsigned mk = 0xFF;
      if (e.m) {
        mk = 0;
        if (mmode == 0) {
          const int4* mp = (const int4*)((const int*)e.m + e.moff + i);
          int4 a = mp[0], b = mp[1];
          mk = (a.x != 0) | ((a.y != 0) << 1) | ((a.z != 0) << 2) | ((a.w != 0) << 3) |
               ((b.x != 0) << 4) | ((b.y != 0) << 5) | ((b.z != 0) << 6) | ((b.w != 0) << 7);
        } else if (mmode == 1) {
          const uint2 mv = *(const uint2*)((const unsigned char*)e.m + e.moff + i);
          const unsigned char* mb = (const unsigned char*)&mv;
          for (int j = 0; j < 8; j++) mk |= (mb[j] != 0) << j;
        } else if (mmode == 2) {
          uint4 mv = *(const uint4*)((const ushort_t*)e.m + e.moff + i);
          const ushort_t* ms = (const ushort_t*)&mv;
          for (int j = 0; j < 8; j++) mk |= (ms[j] != 0) << j;
        } else {
          const uint4* mp = (const uint4*)((const unsigned int*)e.m + e.moff + i);
          uint4 a = mp[0], b = mp[1];
          const unsigned* u = (const unsigned*)&a;
          const unsigned* v = (const unsigned*)&b;
          for (int j = 0; j < 4; j++) mk |= (u[j] != 0) << j;
          for (int j = 0; j < 4; j++) mk |= (v[j] != 0) << (4 + j);
        }
      }
#pragma unroll
      for (int j = 0; j < 8; j++) o[j] = ((mk >> j) & 1) ? wb[j] : (ushort_t)0;
    }
    *(uint4*)(e.o + i) = *(uint4*)o;
  }
}

// ---------------- fused multi-source GEMM, 2-blocks/CU pipelined ----------------
// C[M,N] = sum_s relu(A_s[M,K] * B_s[N,K]^T + bias_s)
// grid = 512 blocks (BM=128 x BN=128 over M=8192, N_pad=1024), block = 256.
struct GemmSrc { const ushort_t* A; const ushort_t* B; const ushort_t* bias; };
struct GemmArgs { GemmSrc s[4]; };

#define SBAR()  asm volatile("s_barrier" ::: "memory")
#define LGKM0() asm volatile("s_waitcnt lgkmcnt(0)" ::: "memory")
#define VMC8()  asm volatile("s_waitcnt vmcnt(8)" ::: "memory")
#define VMC0()  asm volatile("s_waitcnt vmcnt(0)" ::: "memory")

template <int NSRC, bool RELU, bool NGUARD>
__launch_bounds__(256, 2)
__global__ void gemm_multi(GemmArgs args, void* Cv, const int* of32flag,
                           int K, int N_real, int ldc)
{
  // per buffer: A 128x64 bf16 (8192 el) + B 128x64 bf16 (8192 el) = 32KB
  __shared__ __align__(16) ushort_t lds[2][16384];

  const bool of32 = (of32flag != nullptr) && (of32flag[0] != 0);
  __hip_bfloat16* C = (__hip_bfloat16*)Cv;
  float* Cf = (float*)Cv;

  const int tid  = threadIdx.x;
  const int lane = tid & 63;
  const int wave = tid >> 6;         // 0..3
  const int wm = (wave >> 1) * 64;   // 0,64
  const int wn = (wave & 1) * 64;    // 0,64
  const int fr = lane & 15;
  const int kg = lane >> 4;

  // XCD-aware remap (grid=512, nwg%8==0 -> bijective): XCD x = lid&7 owns
  // 8 M-panels x 8 N-tiles; the 8 blocks sharing one A-panel are on the
  // SAME XCD -> A fetched once per XCD L2.
  const int lid = blockIdx.x;
  const int xcd = lid & 7, chunk = lid >> 3;   // chunk 0..63
  const int bm = (xcd * 8 + (chunk >> 3)) * 128;
  const int bn = (chunk & 7) * 128;

  // -------- staging addressing: linear LDS dest, inverse-swizzled source.
  // thread t covers row (t>>3)+32j, 16B-slot (t&7); global slot
  // sg = (t&7) ^ (row&7) = (t&7) ^ ((t>>3)&7)  (32j == 0 mod 8).
  const int rbase = tid >> 3;               // 0..31
  const int sg    = (tid & 7) ^ (rbase & 7);
  const size_t aoff = (size_t)(bm + rbase) * K + sg * 8;
  const size_t boff = (size_t)(bn + rbase) * K + sg * 8;
  const size_t rs32 = (size_t)32 * K;

  auto stage = [&](const ushort_t* gA, const ushort_t* gB, int buf) {
    ushort_t* base = &lds[buf][0];
    ushort_t* lA = base + wave * 512;          // A at elem 0
    ushort_t* lB = base + 8192 + wave * 512;   // B at elem 8192
    gl_lds16(gA,            lA);
    gl_lds16(gA + rs32,     lA + 2048);
    gl_lds16(gA + 2 * rs32, lA + 4096);
    gl_lds16(gA + 3 * rs32, lA + 6144);
    gl_lds16(gB,            lB);
    gl_lds16(gB + rs32,     lB + 2048);
    gl_lds16(gB + 2 * rs32, lB + 4096);
    gl_lds16(gB + 3 * rs32, lB + 6144);
  };

  // -------- fragment read addressing (XOR-swizzled, row&7 == fr&7) --------
  const int s0   = (kg ^ (fr & 7)) * 16;    // byte slot, ks=0; ks=1 -> ^64
  const int arow = (wm + fr) * 128;         // byte offset of A row
  const int brow = 16384 + (wn + fr) * 128; // byte offset of B row

  f32x4 acc[4][4], out_acc[4][4];
#pragma unroll
  for (int i = 0; i < 4; i++)
#pragma unroll
    for (int j = 0; j < 4; j++) {
      acc[i][j] = (f32x4){0.f, 0.f, 0.f, 0.f};
      if (NSRC > 1) out_acc[i][j] = (f32x4){0.f, 0.f, 0.f, 0.f};
    }

  // biases preloaded (keeps vmcnt accounting in the K-loop exact)
  float bpre[NSRC][4];
#pragma unroll
  for (int s = 0; s < NSRC; ++s)
#pragma unroll
    for (int ni = 0; ni < 4; ni++)
      bpre[s][ni] = (float)*(const __hip_bfloat16*)
          (args.s[s].bias + bn + wn + ni * 16 + fr);

  const int TPS = K >> 6;          // K-tiles per source (16 or 32)
  const int NT  = TPS * NSRC;

  // two named fragment sets (static indexing)
  bf16x8 af0[4], bf0[4], af1[4], bf1[4];

  auto rdfrag0 = [&](const char* Lb, int ks) {
    const int so = s0 ^ (ks * 64);
#pragma unroll
    for (int m = 0; m < 4; ++m) af0[m] = *(const bf16x8*)(Lb + arow + m * 2048 + so);
#pragma unroll
    for (int n = 0; n < 4; ++n) bf0[n] = *(const bf16x8*)(Lb + brow + n * 2048 + so);
  };
  auto rdfrag1 = [&](const char* Lb, int ks) {
    const int so = s0 ^ (ks * 64);
#pragma unroll
    for (int m = 0; m < 4; ++m) af1[m] = *(const bf16x8*)(Lb + arow + m * 2048 + so);
#pragma unroll
    for (int n = 0; n < 4; ++n) bf1[n] = *(const bf16x8*)(Lb + brow + n * 2048 + so);
  };
  auto mfma16_0 = [&]() {
    __builtin_amdgcn_s_setprio(1);
#pragma unroll
    for (int mi = 0; mi < 4; mi++)
#pragma unroll
      for (int ni = 0; ni < 4; ni++)
        acc[mi][ni] = __builtin_amdgcn_mfma_f32_16x16x32_bf16(
            af0[mi], bf0[ni], acc[mi][ni], 0, 0, 0);
    __builtin_amdgcn_s_setprio(0);
  };
  auto mfma16_1 = [&]() {
    __builtin_amdgcn_s_setprio(1);
#pragma unroll
    for (int mi = 0; mi < 4; mi++)
#pragma unroll
      for (int ni = 0; ni < 4; ni++)
        acc[mi][ni] = __builtin_amdgcn_mfma_f32_16x16x32_bf16(
            af1[mi], bf1[ni], acc[mi][ni], 0, 0, 0);
    __builtin_amdgcn_s_setprio(0);
  };

  // prologue: stage tiles 0,1; wait tile 0 (leave tile 1's 8 loads flying);
  // pre-read ks=0 fragments of tile 0.
  stage(args.s[0].A + aoff, args.s[0].B + boff, 0);
  {
    const int s1 = 1 / TPS, k1 = (1 % TPS) * 64;
    stage(args.s[s1].A + aoff + k1, args.s[s1].B + boff + k1, 1);
  }
  VMC8();
  SBAR();
  rdfrag0((const char*)&lds[0][0], 0);

  int psrc = 2 / TPS, pk0 = (2 % TPS) * 64;  // next tile to stage
  int csrc = 0, ck = 0;
  int cur = 0;

  for (int t = 0; t < NT; ++t) {
    const char* Lb = (const char*)&lds[cur][0];

    // ---- read ks=1 frags (this tile), covered by MFMA on ks=0 frags ----
    rdfrag1(Lb, 1);
    __builtin_amdgcn_sched_barrier(0);   // pin reads above the MFMA block
    mfma16_0();                          // compiler inserts counted lgkm wait

    // ---- read-retirement fence: all waves' ds_reads of buf cur retired ->
    // safe to overwrite with tile t+2.
    LGKM0();
    SBAR();

    ck += 64;
    const bool srcEnd = (ck == K);
    const bool more2 = (t + 2 < NT);
    if (more2) {
      stage(args.s[psrc].A + aoff + pk0, args.s[psrc].B + boff + pk0, cur);
      pk0 += 64; if (pk0 == K) { pk0 = 0; ++psrc; }
    }

    // ---- counted vmcnt: tile t+1's 8 loads (issued one full tile ago);
    // tile t+2's 8 stay in flight across the barrier. ----
    if (t + 1 < NT) {
      if (more2) VMC8(); else VMC0();
      SBAR();
      // read ks=0 frags of tile t+1 (other buffer), covered by MFMA(ks=1)
      rdfrag0((const char*)&lds[cur ^ 1][0], 0);
    }
    __builtin_amdgcn_sched_barrier(0);   // pin reads above the MFMA block
    mfma16_1();

    // source-boundary epilogue (acc complete only after the ks=1 block)
    if (NSRC > 1 && srcEnd) {
      float bb[4];
#pragma unroll
      for (int s = 0; s < NSRC; ++s)
        if (s == csrc) {
#pragma unroll
          for (int ni = 0; ni < 4; ni++) bb[ni] = bpre[s][ni];
        }
#pragma unroll
      for (int ni = 0; ni < 4; ni++)
#pragma unroll
        for (int mi = 0; mi < 4; mi++)
#pragma unroll
          for (int j = 0; j < 4; j++) {
            float v = acc[mi][ni][j] + bb[ni];
            if (RELU) v = fmaxf(v, 0.0f);
            out_acc[mi][ni][j] += v;
            acc[mi][ni][j] = 0.0f;
          }
      ck = 0; ++csrc;
    }

    cur ^= 1;
  }

  // store: C/D layout col = lane&15, row = (lane>>4)*4 + reg  (verified R3)
#pragma unroll
  for (int ni = 0; ni < 4; ni++) {
    const int c = bn + wn + ni * 16 + fr;
    if (NGUARD && c >= N_real) continue;
#pragma unroll
    for (int mi = 0; mi < 4; mi++) {
      const int r0 = bm + wm + mi * 16 + kg * 4;
#pragma unroll
      for (int j = 0; j < 4; j++) {
        const size_t idx = (size_t)(r0 + j) * ldc + c;
        float v;
        if (NSRC == 1) {
          v = acc[mi][ni][j] + bpre[0][ni];
          if (RELU) v = fmaxf(v, 0.0f);
        } else {
          v = out_acc[mi][ni][j];
        }
        if (of32) Cf[idx] = v;
        else      C[idx]  = (__hip_bfloat16)v;
      }
    }
  }
}

extern "C" void kernel_launch(void* const* d_in, const int* in_sizes, int n_in,
                              void* d_out, int out_size, void* d_ws, size_t ws_size,
                              hipStream_t stream) {
  (void)out_size; (void)ws_size;
  const int Bm = 8192, DIN = 2048, H = 1024, Cn = 1000;
  const size_t HH = (size_t)H * H;

  // ---- size-signature input resolver (verified R3) ----
  struct PO { const void* p; size_t off; };
  PO x{d_in[0], 0}, Wf{d_in[0], 0}, mf{d_in[0], 0}, Wo{d_in[0], 0}, mo{d_in[0], 0};
  PO bf{d_in[0], 0}, bo{d_in[0], 0};
  PO mW[4], mM[4], mB[4], sW[6], sM[6], sB[6];
  for (int i = 0; i < 4; i++) { mW[i] = {d_in[0], 0}; mM[i] = mW[i]; mB[i] = mW[i]; }
  for (int i = 0; i < 6; i++) { sW[i] = {d_in[0], 0}; sM[i] = sW[i]; sB[i] = sW[i]; }

  {
    int c2M = 0, c1M = 0, c1k = 0, cWoMo = 0, c4 = 0, c6 = 0;
    for (int i = 0; i < n_in; i++) {
      const int s = in_sizes[i];
      const void* p = d_in[i];
      switch (s) {
        case 16777216: x = {p, 0}; break;
        case 2097152:  if (c2M++ == 0) Wf = {p, 0}; else mf = {p, 0}; break;
        case 1048576: {
          int j = c1M++;
          if (j < 4)       mW[j]      = {p, 0};
          else if (j < 8)  mM[j - 4]  = {p, 0};
          else if (j < 14) sW[j - 8]  = {p, 0};
          else if (j < 20) sM[j - 14] = {p, 0};
          break;
        }
        case 1024: {
          int j = c1k++;
          if (j == 0)      bf        = {p, 0};
          else if (j < 5)  mB[j - 1] = {p, 0};
          else if (j < 11) sB[j - 5] = {p, 0};
          break;
        }
        case 1024000: if (cWoMo++ == 0) Wo = {p, 0}; else mo = {p, 0}; break;
        case 1000: bo = {p, 0}; break;
        case 4194304:
          for (int t = 0; t < 4; t++) {
            if (c4 == 0) mW[t] = {p, t * HH}; else mM[t] = {p, t * HH};
          }
          c4++; break;
        case 6291456:
          for (int t = 0; t < 6; t++) {
            if (c6 == 0) sW[t] = {p, t * HH}; else sM[t] = {p, t * HH};
          }
          c6++; break;
        case 4096:
          for (int t = 0; t < 4; t++) mB[t] = {p, (size_t)t * H};
          break;
        case 6144:
          for (int t = 0; t < 6; t++) sB[t] = {p, (size_t)t * H};
          break;
        default: break;
      }
    }
  }

  // ---- workspace layout (ushort units) ----
  ushort_t* wsp = (ushort_t*)d_ws;
  size_t off = 0;
  int* flags = (int*)wsp; off += 32;
  ushort_t* xc = wsp + off; off += (size_t)Bm * DIN;
  __hip_bfloat16* r[5];
  for (int i = 0; i < 5; i++) { r[i] = (__hip_bfloat16*)(wsp + off); off += (size_t)Bm * H; }
  ushort_t* wWf = wsp + off; off += (size_t)H * DIN;
  ushort_t* wMain[4];
  for (int i = 0; i < 4; i++) { wMain[i] = wsp + off; off += HH; }
  ushort_t* wSkip[6];
  for (int k = 0; k < 6; k++) { wSkip[k] = wsp + off; off += HH; }
  ushort_t* wWo = wsp + off; off += (size_t)1024 * 1024;  // zero-padded to 1024 rows
  ushort_t* cbf_ = wsp + off; off += 1024;
  ushort_t* cmB[4];
  for (int i = 0; i < 4; i++) { cmB[i] = wsp + off; off += 1024; }
  ushort_t* csB[6];
  for (int k = 0; k < 6; k++) { csB[k] = wsp + off; off += 1024; }
  ushort_t* cbo = wsp + off; off += 1024;                 // tail 1000..1023 zeroed

  // ---- launches ----
  detect_kernel<<<1, 256, 0, stream>>>((const ushort_t*)x.p, (const ushort_t*)mf.p, flags);

  PrepAll p;
  p.e[0]  = { Wf.p, Wf.off, mf.p, mf.off, wWf, H * DIN, H * DIN };
  for (int i = 0; i < 4; i++)
    p.e[1 + i] = { mW[i].p, mW[i].off, mM[i].p, mM[i].off, wMain[i], (int)HH, (int)HH };
  for (int k = 0; k < 6; k++)
    p.e[5 + k] = { sW[k].p, sW[k].off, sM[k].p, sM[k].off, wSkip[k], (int)HH, (int)HH };
  p.e[11] = { Wo.p, Wo.off, mo.p, mo.off, wWo, 1024 * 1024, Cn * H };
  p.e[12] = { bf.p, bf.off, nullptr, 0, cbf_, H, H };
  for (int i = 0; i < 4; i++)
    p.e[13 + i] = { mB[i].p, mB[i].off, nullptr, 0, cmB[i], H, H };
  for (int k = 0; k < 6; k++)
    p.e[17 + k] = { sB[k].p, sB[k].off, nullptr, 0, csB[k], H, H };
  p.e[23] = { bo.p, bo.off, nullptr, 0, cbo, 1024, Cn };
  p.e[24] = { x.p, x.off, nullptr, 0, xc, Bm * DIN, Bm * DIN };   // x conversion
  prep_weights<<<dim3(256, 25), dim3(256), 0, stream>>>(p, flags);

  const dim3 g(512), b(256);

  GemmArgs a0; a0.s[0] = { xc, wWf, cbf_ };
  gemm_multi<1, true, false><<<g, b, 0, stream>>>(a0, r[0], nullptr, DIN, H, H);

  GemmArgs a1; a1.s[0] = { (ushort_t*)r[0], wMain[0], cmB[0] };
  gemm_multi<1, true, false><<<g, b, 0, stream>>>(a1, r[1], nullptr, H, H, H);

  GemmArgs a2;
  a2.s[0] = { (ushort_t*)r[1], wMain[1], cmB[1] };
  a2.s[1] = { (ushort_t*)r[0], wSkip[0], csB[0] };
  gemm_multi<2, true, false><<<g, b, 0, stream>>>(a2, r[2], nullptr, H, H, H);

  GemmArgs a3;
  a3.s[0] = { (ushort_t*)r[2], wMain[2], cmB[2] };
  a3.s[1] = { (ushort_t*)r[0], wSkip[1], csB[1] };
  a3.s[2] = { (ushort_t*)r[1], wSkip[2], csB[2] };
  gemm_multi<3, true, false><<<g, b, 0, stream>>>(a3, r[3], nullptr, H, H, H);

  GemmArgs a4;
  a4.s[0] = { (ushort_t*)r[3], wMain[3], cmB[3] };
  a4.s[1] = { (ushort_t*)r[0], wSkip[3], csB[3] };
  a4.s[2] = { (ushort_t*)r[1], wSkip[4], csB[4] };
  a4.s[3] = { (ushort_t*)r[2], wSkip[5], csB[5] };
  gemm_multi<4, true, false><<<g, b, 0, stream>>>(a4, r[4], nullptr, H, H, H);

  GemmArgs ao; ao.s[0] = { (ushort_t*)r[4], wWo, cbo };
  gemm_multi<1, false, true><<<g, b, 0, stream>>>(ao, d_out, flags, H, Cn, Cn);
}